// Round 2
// baseline (1077.860 us; speedup 1.0000x reference)
//
#include <hip/hip_runtime.h>

typedef __bf16 bf16;
typedef bf16 bf16x8 __attribute__((ext_vector_type(8)));
typedef float f32x4 __attribute__((ext_vector_type(4)));

#define NUM_MOLS 2000
#define APM 50
#define NA (NUM_MOLS*APM+1)      // 100001
#define NB (2*NUM_MOLS*APM+1)    // 200001
#define MAX_NB 6
#define AF 133
#define BFD 147
#define H 300
#define HP 320
#define KI 160                   // padded BOND_FDIM
#define KO 448                   // padded concat dim: 133 + 3 pad + 300 + 12 pad
#define AOFF 136                 // a_message column offset inside cat

// ---------------- weight prep (pad + transpose to [N][K] bf16) ----------------
__global__ void k_prep_wi(const float* __restrict__ Wi, bf16* __restrict__ Wt){ // Wt [HP][KI]
    int i = blockIdx.x*256 + threadIdx.x; if (i >= HP*KI) return;
    int n = i / KI, k = i % KI;
    float v = (k < BFD && n < H) ? Wi[k*H + n] : 0.f;
    Wt[i] = (bf16)v;
}
__global__ void k_prep_wh(const float* __restrict__ Wh, bf16* __restrict__ Wt){ // Wt [HP][HP]
    int i = blockIdx.x*256 + threadIdx.x; if (i >= HP*HP) return;
    int n = i / HP, k = i % HP;
    float v = (k < H && n < H) ? Wh[k*H + n] : 0.f;
    Wt[i] = (bf16)v;
}
__global__ void k_prep_wo(const float* __restrict__ Wo, bf16* __restrict__ Wt){ // Wt [HP][KO]
    int i = blockIdx.x*256 + threadIdx.x; if (i >= HP*KO) return;
    int n = i / KO, k = i % KO;
    float v = 0.f;
    if (n < H) {
        if (k < AF)                       v = Wo[k*H + n];
        else if (k >= AOFF && k < AOFF+H) v = Wo[(k - AOFF + AF)*H + n];
    }
    Wt[i] = (bf16)v;
}
// f_bonds fp32 [NB][147] -> bf16 [NB][160] zero-padded
__global__ void k_conv_fb(const float* __restrict__ fb, bf16* __restrict__ out){
    long i = (long)blockIdx.x*256 + threadIdx.x; if (i >= (long)NB*KI) return;
    int k = (int)(i % KI); long b = i / KI;
    float v = (k < BFD) ? fb[b*BFD + k] : 0.f;
    out[i] = (bf16)v;
}
// cat [NA][KO]: cols 0..135 <- f_atoms (133 real + 3 zero), cols 440..447 <- 0
__global__ void k_init_cat(const float* __restrict__ fa, bf16* __restrict__ cat){
    long u = (long)blockIdx.x*256 + threadIdx.x; if (u >= (long)NA*18) return;
    int c = (int)(u % 18); long a = u / 18;
    bf16x8 v;
    if (c < 17) {
        int c0 = c*8;
        #pragma unroll
        for (int j=0;j<8;j++){
            int col = c0 + j;
            float f = (col < AF) ? fa[a*AF + col] : 0.f;
            v[j] = (bf16)f;
        }
        *(bf16x8*)(cat + a*KO + c0) = v;
    } else {
        #pragma unroll
        for (int j=0;j<8;j++) v[j] = (bf16)0.f;
        *(bf16x8*)(cat + a*KO + 440) = v;
    }
}

// ---------------- gather: a_message[a] = sum_k w_bonds[a2b[a,k]] * msg[a2b[a,k]] ----------------
__global__ void k_gather_amsg(const bf16* __restrict__ msg, const int* __restrict__ a2b,
                              const float* __restrict__ w_bonds,
                              bf16* __restrict__ out, int out_stride, int col_off, int nchunks){
    long u = (long)blockIdx.x*256 + threadIdx.x;
    if (u >= (long)NA*nchunks) return;
    int c = (int)(u % nchunks); long a = u / nchunks;
    int c0 = c*8;
    float acc[8] = {0,0,0,0,0,0,0,0};
    #pragma unroll
    for (int k=0;k<MAX_NB;k++){
        int b = a2b[a*MAX_NB + k];
        float w = w_bonds[b];
        bf16x8 m = *(const bf16x8*)(msg + (long)b*HP + c0);
        #pragma unroll
        for (int j=0;j<8;j++) acc[j] += w * (float)m[j];
    }
    bf16x8 o;
    #pragma unroll
    for (int j=0;j<8;j++) o[j] = (bf16)acc[j];
    *(bf16x8*)(out + (long)a*out_stride + col_off + c0) = o;
}

// ---------------- bond update pre-GEMM: pre[b] = amsg[b2a[b]] - msg[b2revb[b]]*w_bonds[b] ----------------
__global__ void k_bond_pre(const bf16* __restrict__ amsg, const bf16* __restrict__ msg,
                           const int* __restrict__ b2a, const int* __restrict__ b2revb,
                           const float* __restrict__ w_bonds, bf16* __restrict__ pre){
    long u = (long)blockIdx.x*256 + threadIdx.x;
    if (u >= (long)NB*40) return;
    int c = (int)(u % 40); long b = u / 40;
    int c0 = c*8;
    int ia = b2a[b]; int ib = b2revb[b]; float w = w_bonds[b];
    bf16x8 av = *(const bf16x8*)(amsg + (long)ia*HP + c0);
    bf16x8 mv = *(const bf16x8*)(msg + (long)ib*HP + c0);
    bf16x8 o;
    #pragma unroll
    for (int j=0;j<8;j++) o[j] = (bf16)((float)av[j] - (float)mv[j]*w);
    *(bf16x8*)(pre + (long)b*HP + c0) = o;
}

// ---------------- MFMA GEMM: out = relu(A@B (+add) (+bias)), optional raw out1 ----------------
// A [M][lda] bf16 row-major (K = loop bound), Bt [HP][K] bf16 (transposed weights, ldb=K)
__launch_bounds__(256)
__global__ void k_gemm(const bf16* __restrict__ A, int lda, int K, int M,
                       const bf16* __restrict__ Bt,
                       const bf16* __restrict__ add, const float* __restrict__ bias,
                       bf16* __restrict__ out0, bf16* __restrict__ out1){
    __shared__ bf16 As[64][40];
    __shared__ bf16 Bs[64][40];
    int row0 = blockIdx.x * 64;
    int n0   = blockIdx.y * 64;
    int t = threadIdx.x;
    int wave = t >> 6, lane = t & 63;
    int wm = (wave >> 1) * 32, wn = (wave & 1) * 32;
    int kr = lane >> 4, lr = lane & 15;
    f32x4 acc[2][2] = {};
    int sr = t >> 2;          // staging row 0..63
    int sc = (t & 3) * 8;     // staging col chunk

    for (int k0 = 0; k0 < K; k0 += 32) {
        long ar = row0 + sr; if (ar >= M) ar = M - 1;
        bf16x8 av = *(const bf16x8*)(A  + ar*(long)lda + k0 + sc);
        bf16x8 bv = *(const bf16x8*)(Bt + (long)(n0 + sr)*K + k0 + sc);
        __syncthreads();
        *(bf16x8*)(&As[sr][sc]) = av;
        *(bf16x8*)(&Bs[sr][sc]) = bv;
        __syncthreads();
        bf16x8 af0 = *(const bf16x8*)(&As[wm      + lr][kr*8]);
        bf16x8 af1 = *(const bf16x8*)(&As[wm + 16 + lr][kr*8]);
        bf16x8 bf0 = *(const bf16x8*)(&Bs[wn      + lr][kr*8]);
        bf16x8 bf1 = *(const bf16x8*)(&Bs[wn + 16 + lr][kr*8]);
        acc[0][0] = __builtin_amdgcn_mfma_f32_16x16x32_bf16(af0, bf0, acc[0][0], 0,0,0);
        acc[0][1] = __builtin_amdgcn_mfma_f32_16x16x32_bf16(af0, bf1, acc[0][1], 0,0,0);
        acc[1][0] = __builtin_amdgcn_mfma_f32_16x16x32_bf16(af1, bf0, acc[1][0], 0,0,0);
        acc[1][1] = __builtin_amdgcn_mfma_f32_16x16x32_bf16(af1, bf1, acc[1][1], 0,0,0);
    }

    #pragma unroll
    for (int fm=0; fm<2; fm++)
    #pragma unroll
    for (int fn=0; fn<2; fn++)
    #pragma unroll
    for (int r=0; r<4; r++){
        int row = row0 + wm + fm*16 + kr*4 + r;
        if (row >= M) continue;
        int col = n0 + wn + fn*16 + lr;
        float v = acc[fm][fn][r];
        if (add)  v += (float)add[(long)row*HP + col];
        if (bias) v += (col < H) ? bias[col] : 0.f;
        if (out1) out1[(long)row*HP + col] = (bf16)v;
        out0[(long)row*HP + col] = (bf16)fmaxf(v, 0.f);
    }
}

// ---------------- per-molecule weighted mean ----------------
__global__ void k_seg(const bf16* __restrict__ ah, const float* __restrict__ w_atoms,
                      const float* __restrict__ dop, float* __restrict__ out){
    int m = blockIdx.x; int t = threadIdx.x;
    __shared__ float ws_sum;
    float w = 0.f;
    if (t < APM) w = w_atoms[1 + m*APM + t];
    if (t < 64) {
        for (int o=32;o;o>>=1) w += __shfl_down(w, o);
        if (t==0) ws_sum = w;
    }
    __syncthreads();
    float scale = dop[m] / ws_sum;
    for (int h = t; h < H; h += 256) {
        float acc = 0.f;
        for (int j=0;j<APM;j++){
            int a = 1 + m*APM + j;
            acc += (float)ah[(long)a*HP + h] * w_atoms[a];
        }
        out[m*H + h] = acc * scale;
    }
}

// ---------------- diagnostic fallback: zero the output ----------------
__global__ void k_zero(float* __restrict__ out, int n){
    int i = blockIdx.x*256 + threadIdx.x;
    if (i < n) out[i] = 0.f;
}

extern "C" void kernel_launch(void* const* d_in, const int* in_sizes, int n_in,
                              void* d_out, int out_size, void* d_ws, size_t ws_size,
                              hipStream_t stream) {
    const float* f_atoms = (const float*)d_in[0];
    const float* f_bonds = (const float*)d_in[1];
    const float* w_atoms = (const float*)d_in[2];
    const float* w_bonds = (const float*)d_in[3];
    const float* dop     = (const float*)d_in[4];
    const float* W_i     = (const float*)d_in[5];
    const float* W_h     = (const float*)d_in[6];
    const float* W_o     = (const float*)d_in[7];
    const float* b_o     = (const float*)d_in[8];
    const int*   a2b     = (const int*)d_in[9];
    const int*   b2a     = (const int*)d_in[10];
    const int*   b2revb  = (const int*)d_in[11];
    float* out = (float*)d_out;
    (void)in_sizes; (void)n_in;

    // ---- workspace layout with lifetime aliasing (total ~449 MB) ----
    const size_t R_BIG = ((size_t)NB*HP*2 + 255) & ~(size_t)255;   // 128.0 MB
    const size_t R_ATM = ((size_t)NA*HP*2 + 255) & ~(size_t)255;   //  64.0 MB
    const size_t R_WI  = ((size_t)HP*KI*2 + 255) & ~(size_t)255;
    const size_t R_WH  = ((size_t)HP*HP*2 + 255) & ~(size_t)255;
    const size_t R_WO  = ((size_t)HP*KO*2 + 255) & ~(size_t)255;
    const size_t need  = 3*R_BIG + R_ATM + R_WI + R_WH + R_WO;

    if (ws_size < need) {
        // diagnostic: clean zero output instead of an OOB fault
        k_zero<<<(out_size+255)/256, 256, 0, stream>>>(out, out_size);
        return;
    }

    char* ws = (char*)d_ws;
    char* region1 = ws;                    // fb -> pre -> cat
    char* region2 = ws + R_BIG;            // inp
    char* region3 = ws + 2*R_BIG;          // msg
    char* region4 = ws + 3*R_BIG;          // amsg -> atom_hiddens
    bf16* wit = (bf16*)(ws + 3*R_BIG + R_ATM);
    bf16* wht = (bf16*)((char*)wit + R_WI);
    bf16* wot = (bf16*)((char*)wht + R_WH);

    bf16* fb   = (bf16*)region1;
    bf16* pre  = (bf16*)region1;
    bf16* cat  = (bf16*)region1;
    bf16* inp  = (bf16*)region2;
    bf16* msg  = (bf16*)region3;
    bf16* amsg = (bf16*)region4;
    bf16* ah   = (bf16*)region4;

    k_prep_wi<<<(HP*KI+255)/256, 256, 0, stream>>>(W_i, wit);
    k_prep_wh<<<(HP*HP+255)/256, 256, 0, stream>>>(W_h, wht);
    k_prep_wo<<<(HP*KO+255)/256, 256, 0, stream>>>(W_o, wot);
    k_conv_fb<<<(int)(((long)NB*KI+255)/256), 256, 0, stream>>>(f_bonds, fb);

    // inp = f_bonds@W_i ; msg = relu(inp)   (consumes fb, frees region1)
    k_gemm<<<dim3((NB+63)/64, HP/64), 256, 0, stream>>>(fb, KI, KI, NB, wit,
                                                        nullptr, nullptr, msg, inp);
    for (int d=0; d<2; d++){
        k_gather_amsg<<<(int)(((long)NA*40+255)/256), 256, 0, stream>>>(
            msg, a2b, w_bonds, amsg, HP, 0, 40);
        k_bond_pre<<<(int)(((long)NB*40+255)/256), 256, 0, stream>>>(
            amsg, msg, b2a, b2revb, w_bonds, pre);
        // msg = relu(inp + pre@W_h)
        k_gemm<<<dim3((NB+63)/64, HP/64), 256, 0, stream>>>(pre, HP, HP, NB, wht,
                                                            inp, nullptr, msg, nullptr);
    }
    // cat init AFTER loop (region1's pre is dead now); then final neighbor-sum
    // written straight into cat cols [136,439]
    k_init_cat<<<(int)(((long)NA*18+255)/256), 256, 0, stream>>>(f_atoms, cat);
    k_gather_amsg<<<(int)(((long)NA*38+255)/256), 256, 0, stream>>>(
        msg, a2b, w_bonds, cat, KO, AOFF, 38);
    // atom_hiddens = relu(cat@W_o + b_o) -> region4 (amsg dead)
    k_gemm<<<dim3((NA+63)/64, HP/64), 256, 0, stream>>>(cat, KO, KO, NA, wot,
                                                        nullptr, b_o, ah, nullptr);
    k_seg<<<NUM_MOLS, 256, 0, stream>>>(ah, w_atoms, dop, out);
}

// Round 3
// 833.563 us; speedup vs baseline: 1.2931x; 1.2931x over previous
//
#include <hip/hip_runtime.h>

typedef __bf16 bf16;
typedef bf16 bf16x8 __attribute__((ext_vector_type(8)));
typedef float f32x4 __attribute__((ext_vector_type(4)));

#define NUM_MOLS 2000
#define APM 50
#define NA (NUM_MOLS*APM+1)      // 100001
#define NB (2*NUM_MOLS*APM+1)    // 200001
#define MAX_NB 6
#define AF 133
#define BFD 147
#define H 300
#define HP 320
#define KIP 192                  // padded BOND_FDIM (3 x BK)
#define KO 448                   // padded concat dim: 133 + 3 pad + 300 + 12 pad
#define AOFF 136                 // a_message column offset inside cat
#define BM 64
#define BKT 64
#define LDT 72                   // padded LDS stride (144 B: 2-way conflict max)

// ---------------- weight prep (pad + transpose to [N][K] bf16) ----------------
__global__ void k_prep_wi(const float* __restrict__ Wi, bf16* __restrict__ Wt){ // [HP][KIP]
    int i = blockIdx.x*256 + threadIdx.x; if (i >= HP*KIP) return;
    int n = i / KIP, k = i % KIP;
    float v = (k < BFD && n < H) ? Wi[k*H + n] : 0.f;
    Wt[i] = (bf16)v;
}
__global__ void k_prep_wh(const float* __restrict__ Wh, bf16* __restrict__ Wt){ // [HP][HP]
    int i = blockIdx.x*256 + threadIdx.x; if (i >= HP*HP) return;
    int n = i / HP, k = i % HP;
    float v = (k < H && n < H) ? Wh[k*H + n] : 0.f;
    Wt[i] = (bf16)v;
}
__global__ void k_prep_wo(const float* __restrict__ Wo, bf16* __restrict__ Wt){ // [HP][KO]
    int i = blockIdx.x*256 + threadIdx.x; if (i >= HP*KO) return;
    int n = i / KO, k = i % KO;
    float v = 0.f;
    if (n < H) {
        if (k < AF)                       v = Wo[k*H + n];
        else if (k >= AOFF && k < AOFF+H) v = Wo[(k - AOFF + AF)*H + n];
    }
    Wt[i] = (bf16)v;
}
// cat [NA][KO]: cols 0..135 <- f_atoms (133 real + 3 zero), cols 440..447 <- 0
__global__ void k_init_cat(const float* __restrict__ fa, bf16* __restrict__ cat){
    long u = (long)blockIdx.x*256 + threadIdx.x; if (u >= (long)NA*18) return;
    int c = (int)(u % 18); long a = u / 18;
    bf16x8 v;
    if (c < 17) {
        int c0 = c*8;
        #pragma unroll
        for (int j=0;j<8;j++){
            int col = c0 + j;
            float f = (col < AF) ? fa[a*AF + col] : 0.f;
            v[j] = (bf16)f;
        }
        *(bf16x8*)(cat + a*KO + c0) = v;
    } else {
        #pragma unroll
        for (int j=0;j<8;j++) v[j] = (bf16)0.f;
        *(bf16x8*)(cat + a*KO + 440) = v;
    }
}

// ---- gather: out[a] = sum_k w_bonds[a2b[a,k]] * relu(msgraw[a2b[a,k]]) ----
__global__ void k_gather_amsg(const bf16* __restrict__ msg, const int* __restrict__ a2b,
                              const float* __restrict__ w_bonds,
                              bf16* __restrict__ out, int out_stride, int col_off, int nchunks){
    long u = (long)blockIdx.x*256 + threadIdx.x;
    if (u >= (long)NA*nchunks) return;
    int c = (int)(u % nchunks); long a = u / nchunks;
    int c0 = c*8;
    float acc[8] = {0,0,0,0,0,0,0,0};
    #pragma unroll
    for (int k=0;k<MAX_NB;k++){
        int b = a2b[a*MAX_NB + k];
        float w = w_bonds[b];
        bf16x8 m = *(const bf16x8*)(msg + (long)b*HP + c0);
        #pragma unroll
        for (int j=0;j<8;j++) acc[j] += w * fmaxf((float)m[j], 0.f);
    }
    bf16x8 o;
    #pragma unroll
    for (int j=0;j<8;j++) o[j] = (bf16)acc[j];
    *(bf16x8*)(out + (long)a*out_stride + col_off + c0) = o;
}

// ---------------- full-width MFMA GEMM, BM=64 x BN=320, BK=64 ----------------
// MODE 0: A = f_bonds fp32 [M][147], convert+pad on stage     (GEMM1)
// MODE 1: A[b] = amsg[b2a[b]] - relu(msgsrc[b2revb[b]])*w_b   (GEMM2/3, fused bond_pre)
// MODE 2: A = cat bf16 [M][KO] direct; +bias +relu            (GEMM4)
// Bt: [HP][K] bf16 (weights pre-transposed, zero-padded). out: [M][HP] bf16.
template<int MODE>
__global__ __launch_bounds__(512, 4)
void k_gemm(const void* __restrict__ Asrc, const bf16* __restrict__ msgsrc,
            const int* __restrict__ b2a, const int* __restrict__ b2revb,
            const float* __restrict__ w_bonds,
            const bf16* __restrict__ Bt, int K, int M,
            const bf16* __restrict__ add, const float* __restrict__ bias,
            bf16* __restrict__ out)
{
    __shared__ bf16 As[BM][LDT];   // 9216 B
    __shared__ bf16 Bs[HP][LDT];   // 46080 B
    int t = threadIdx.x;
    int row0 = blockIdx.x * BM;
    int wave = t >> 6, lane = t & 63;
    int wm = wave >> 2, wn = wave & 3;     // 2 x 4 wave grid
    int kr = lane >> 4, lr = lane & 15;
    f32x4 acc[2][5] = {};

    int sr = t >> 3;            // A staging row 0..63
    int sc = (t & 7) * 8;       // A staging col chunk
    int arow = row0 + sr; if (arow >= M) arow = M - 1;
    int ia = 0, ir = 0; float w = 0.f;
    if (MODE == 1) { ia = b2a[arow]; ir = b2revb[arow]; w = w_bonds[arow]; }

    for (int k0 = 0; k0 < K; k0 += BKT) {
        bf16x8 av;
        if (MODE == 0) {
            const float* fb = (const float*)Asrc;
            #pragma unroll
            for (int j = 0; j < 8; j++) {
                int k = k0 + sc + j;
                av[j] = (bf16)(k < BFD ? fb[(long)arow*BFD + k] : 0.f);
            }
        } else if (MODE == 1) {
            const bf16* am = (const bf16*)Asrc;
            bf16x8 a8 = *(const bf16x8*)(am     + (long)ia*HP + k0 + sc);
            bf16x8 m8 = *(const bf16x8*)(msgsrc + (long)ir*HP + k0 + sc);
            #pragma unroll
            for (int j = 0; j < 8; j++)
                av[j] = (bf16)((float)a8[j] - fmaxf((float)m8[j], 0.f) * w);
        } else {
            av = *(const bf16x8*)((const bf16*)Asrc + (long)arow*KO + k0 + sc);
        }
        bf16x8 bv[5];
        #pragma unroll
        for (int i = 0; i < 5; i++) {
            int c = t + 512*i;
            int br = c >> 3, bc = (c & 7) * 8;
            bv[i] = *(const bf16x8*)(Bt + (long)br*K + k0 + bc);
        }
        __syncthreads();
        *(bf16x8*)(&As[sr][sc]) = av;
        #pragma unroll
        for (int i = 0; i < 5; i++) {
            int c = t + 512*i;
            int br = c >> 3, bc = (c & 7) * 8;
            *(bf16x8*)(&Bs[br][bc]) = bv[i];
        }
        __syncthreads();
        #pragma unroll
        for (int kk = 0; kk < BKT; kk += 32) {
            bf16x8 af[2], bfr[5];
            #pragma unroll
            for (int m = 0; m < 2; m++)
                af[m] = *(const bf16x8*)(&As[wm*32 + m*16 + lr][kk + kr*8]);
            #pragma unroll
            for (int n = 0; n < 5; n++)
                bfr[n] = *(const bf16x8*)(&Bs[wn*80 + n*16 + lr][kk + kr*8]);
            #pragma unroll
            for (int m = 0; m < 2; m++)
                #pragma unroll
                for (int n = 0; n < 5; n++)
                    acc[m][n] = __builtin_amdgcn_mfma_f32_16x16x32_bf16(af[m], bfr[n], acc[m][n], 0, 0, 0);
        }
    }
    #pragma unroll
    for (int m = 0; m < 2; m++)
    #pragma unroll
    for (int n = 0; n < 5; n++)
    #pragma unroll
    for (int r = 0; r < 4; r++) {
        int row = row0 + wm*32 + m*16 + kr*4 + r;
        if (row >= M) continue;
        int col = wn*80 + n*16 + lr;
        float v = acc[m][n][r];
        if (add)  v += (float)add[(long)row*HP + col];
        if (bias) v += (col < H) ? bias[col] : 0.f;
        if (MODE == 2) v = fmaxf(v, 0.f);
        out[(long)row*HP + col] = (bf16)v;
    }
}

// ---------------- per-molecule weighted mean ----------------
__global__ void k_seg(const bf16* __restrict__ ah, const float* __restrict__ w_atoms,
                      const float* __restrict__ dop, float* __restrict__ out){
    int m = blockIdx.x; int t = threadIdx.x;
    __shared__ float ws_sum;
    float w = 0.f;
    if (t < APM) w = w_atoms[1 + m*APM + t];
    if (t < 64) {
        for (int o=32;o;o>>=1) w += __shfl_down(w, o);
        if (t==0) ws_sum = w;
    }
    __syncthreads();
    float scale = dop[m] / ws_sum;
    for (int h = t; h < H; h += 256) {
        float acc = 0.f;
        for (int j=0;j<APM;j++){
            int a = 1 + m*APM + j;
            acc += (float)ah[(long)a*HP + h] * w_atoms[a];
        }
        out[m*H + h] = acc * scale;
    }
}

__global__ void k_zero(float* __restrict__ out, int n){
    int i = blockIdx.x*256 + threadIdx.x;
    if (i < n) out[i] = 0.f;
}

extern "C" void kernel_launch(void* const* d_in, const int* in_sizes, int n_in,
                              void* d_out, int out_size, void* d_ws, size_t ws_size,
                              hipStream_t stream) {
    const float* f_atoms = (const float*)d_in[0];
    const float* f_bonds = (const float*)d_in[1];
    const float* w_atoms = (const float*)d_in[2];
    const float* w_bonds = (const float*)d_in[3];
    const float* dop     = (const float*)d_in[4];
    const float* W_i     = (const float*)d_in[5];
    const float* W_h     = (const float*)d_in[6];
    const float* W_o     = (const float*)d_in[7];
    const float* b_o     = (const float*)d_in[8];
    const int*   a2b     = (const int*)d_in[9];
    const int*   b2a     = (const int*)d_in[10];
    const int*   b2revb  = (const int*)d_in[11];
    float* out = (float*)d_out;
    (void)in_sizes; (void)n_in;

    const size_t R_BIG = ((size_t)NB*HP*2 + 255) & ~(size_t)255;   // 128 MB
    const size_t R_ATM = ((size_t)NA*HP*2 + 255) & ~(size_t)255;   //  64 MB
    const size_t R_WI  = ((size_t)HP*KIP*2 + 255) & ~(size_t)255;
    const size_t R_WH  = ((size_t)HP*HP*2 + 255) & ~(size_t)255;
    const size_t R_WO  = ((size_t)HP*KO*2 + 255) & ~(size_t)255;
    const size_t need  = 3*R_BIG + R_ATM + R_WI + R_WH + R_WO;

    if (ws_size < need) {
        k_zero<<<(out_size+255)/256, 256, 0, stream>>>(out, out_size);
        return;
    }

    char* ws = (char*)d_ws;
    bf16* inp  = (bf16*)ws;                    // GEMM1 out (raw), live to end of GEMM3
    bf16* msgA = (bf16*)(ws + R_BIG);          // GEMM2 out (raw); later aliased by cat
    bf16* msgB = (bf16*)(ws + 2*R_BIG);        // GEMM3 out (raw)
    bf16* amsg = (bf16*)(ws + 3*R_BIG);        // neighbor sums; later aliased by ah
    bf16* wit  = (bf16*)(ws + 3*R_BIG + R_ATM);
    bf16* wht  = (bf16*)((char*)wit + R_WI);
    bf16* wot  = (bf16*)((char*)wht + R_WH);
    bf16* cat  = msgA;                         // alias: msgA dead after GEMM3
    bf16* ah   = amsg;                         // alias: amsg dead after GEMM3

    k_prep_wi<<<(HP*KIP+255)/256, 256, 0, stream>>>(W_i, wit);
    k_prep_wh<<<(HP*HP+255)/256, 256, 0, stream>>>(W_h, wht);
    k_prep_wo<<<(HP*KO+255)/256, 256, 0, stream>>>(W_o, wot);

    const int GB = (NB + BM - 1) / BM;   // 3126
    const int GA = (NA + BM - 1) / BM;   // 1563

    // inp = f_bonds @ W_i   (raw; relu applied on every read)
    k_gemm<0><<<GB, 512, 0, stream>>>(f_bonds, nullptr, nullptr, nullptr, nullptr,
                                      wit, KIP, NB, nullptr, nullptr, inp);
    // depth 1
    k_gather_amsg<<<(int)(((long)NA*40+255)/256), 256, 0, stream>>>(
        inp, a2b, w_bonds, amsg, HP, 0, 40);
    k_gemm<1><<<GB, 512, 0, stream>>>(amsg, inp, b2a, b2revb, w_bonds,
                                      wht, HP, NB, inp, nullptr, msgA);
    // depth 2
    k_gather_amsg<<<(int)(((long)NA*40+255)/256), 256, 0, stream>>>(
        msgA, a2b, w_bonds, amsg, HP, 0, 40);
    k_gemm<1><<<GB, 512, 0, stream>>>(amsg, msgA, b2a, b2revb, w_bonds,
                                      wht, HP, NB, inp, nullptr, msgB);
    // readout
    k_init_cat<<<(int)(((long)NA*18+255)/256), 256, 0, stream>>>(f_atoms, cat);
    k_gather_amsg<<<(int)(((long)NA*38+255)/256), 256, 0, stream>>>(
        msgB, a2b, w_bonds, cat, KO, AOFF, 38);
    k_gemm<2><<<GA, 512, 0, stream>>>(cat, nullptr, nullptr, nullptr, nullptr,
                                      wot, KO, NA, nullptr, b_o, ah);
    k_seg<<<NUM_MOLS, 256, 0, stream>>>(ah, w_atoms, dop, out);
}